// Round 7
// baseline (218.991 us; speedup 1.0000x reference)
//
#include <hip/hip_runtime.h>
#include <hip/hip_bf16.h>

// Self_Attention: conv1d(k=7,pad=3)+BN on q/k/v -> MHA (H=8, DH=64) -> LayerNorm
// R7: revert attn XCD swizzle (R6 regression -38us, identity mapping faster);
// softmax in exp2 domain (log2e folded into Q scale) + defer-max (T13, THR=8).
// conv/cast/prep/transpose/lnorm unchanged from R6.

#define B_ 4
#define S_ 2048
#define DIN_ 512
#define DOUT_ 512
#define H_ 8
#define DH_ 64
#define EPS_ 1e-5f
#define SP_ 2054   // S + 6 halo rows

using bf16x8 = __attribute__((ext_vector_type(8))) short;
using f32x4  = __attribute__((ext_vector_type(4))) float;

__device__ __forceinline__ unsigned short f2bf(float x) {
    union { float f; unsigned u; } v; v.f = x;
    unsigned r = v.u + 0x7FFF + ((v.u >> 16) & 1);
    return (unsigned short)(r >> 16);
}

__device__ __forceinline__ unsigned cvt2(float lo, float hi) {
    unsigned r;
    asm("v_cvt_pk_bf16_f32 %0, %1, %2" : "=v"(r) : "v"(lo), "v"(hi));
    return r;
}

__device__ __forceinline__ float fexp2(float x) {
    float r;
    asm("v_exp_f32 %0, %1" : "=v"(r) : "v"(x));
    return r;
}

typedef __attribute__((address_space(1))) const unsigned int GU32;
typedef __attribute__((address_space(3))) unsigned int LU32;
__device__ __forceinline__ void gl_lds16(const void* g, void* l) {
    __builtin_amdgcn_global_load_lds((GU32*)g, (LU32*)l, 16, 0, 0);
}

// ---------------- kernel 0: cast q/k/v f32 -> bf16 padded [3][4][SP][512] ----
__global__ void cast_x(const float* __restrict__ q, const float* __restrict__ k,
                       const float* __restrict__ v, unsigned short* __restrict__ xb) {
    int i = blockIdx.x * 256 + threadIdx.x;
    int row = i >> 6;
    int cin = (i & 63) * 8;
    int tb = row / SP_;
    int pr = row - tb * SP_;
    int tensor = tb >> 2;
    int b = tb & 3;
    unsigned short* dst = xb + (size_t)row * DIN_ + cin;
    if (pr < 3 || pr >= SP_ - 3) {
        *reinterpret_cast<uint4*>(dst) = make_uint4(0, 0, 0, 0);
    } else {
        const float* src = (tensor == 0 ? q : (tensor == 1 ? k : v)) +
                           ((size_t)b * S_ + (pr - 3)) * DIN_ + cin;
        float4 a0 = *reinterpret_cast<const float4*>(src);
        float4 a1 = *reinterpret_cast<const float4*>(src + 4);
        uint4 o;
        o.x = cvt2(a0.x, a0.y); o.y = cvt2(a0.z, a0.w);
        o.z = cvt2(a1.x, a1.y); o.w = cvt2(a1.z, a1.w);
        *reinterpret_cast<uint4*>(dst) = o;
    }
}

// ---------------- kernel 1: fold BN into weights, cast to bf16 [t][co][ci] ----
__global__ void prep_w(const float* __restrict__ w, const float* __restrict__ cb,
                       const float* __restrict__ gamma, const float* __restrict__ beta,
                       const float* __restrict__ mean, const float* __restrict__ var,
                       unsigned short* __restrict__ w_eff, float* __restrict__ b_eff) {
    int gid = blockIdx.x * blockDim.x + threadIdx.x;
    if (gid < DOUT_) {
        float sc = gamma[gid] * rsqrtf(var[gid] + EPS_);
        b_eff[gid] = (cb[gid] - mean[gid]) * sc + beta[gid];
    }
    int total = 7 * DOUT_ * DIN_;
    for (int i = gid; i < total; i += gridDim.x * blockDim.x) {
        int t = i / (DOUT_ * DIN_);
        int rem = i - t * (DOUT_ * DIN_);
        int co = rem >> 9;
        int ci = rem & 511;
        float sc = gamma[co] * rsqrtf(var[co] + EPS_);
        w_eff[i] = f2bf(w[(co * DIN_ + ci) * 7 + t] * sc);
    }
}

// ---------------- kernel 2: conv+BN implicit GEMM, gl_lds pipelined ----------
__global__ __launch_bounds__(256, 2) void conv_bn(
        const unsigned short* __restrict__ xb,
        const unsigned short* __restrict__ w_eff,
        const float* __restrict__ b_eff,
        unsigned short* __restrict__ out3) {
    __shared__ alignas(16) unsigned short As[2][192 * 32];
    __shared__ alignas(16) unsigned short Bs[3][256 * 32];

    int orig = blockIdx.x;
    int bid = (orig & 7) * 48 + (orig >> 3);   // XCD-chunked, 384 = 8*48
    int tensor = bid >> 7;
    int rem = bid & 127;
    int batch = rem >> 5;
    int stile = (rem >> 1) & 15;
    int cotile = rem & 1;
    int s0 = stile * 128;
    int co0 = cotile * 256;

    const unsigned short* xp = xb + (size_t)(tensor * 4 + batch) * SP_ * DIN_;
    unsigned short* out = out3 + (size_t)tensor * (B_ * S_ * DOUT_) +
                          (size_t)batch * S_ * DOUT_;

    const int tid = threadIdx.x;
    const int l = tid & 63;
    const int wv = tid >> 6;
    const int g = l >> 4;
    const int c16 = l & 15;
    const int wrow = (wv >> 1) * 64;
    const int wcol = (wv & 1) * 128;

    const int dr4 = l >> 2;
    const int sch = ((l & 3) ^ (dr4 & 3)) << 3;

#define STAGE_A(cc, buf) do {                                                   \
        _Pragma("unroll")                                                       \
        for (int j = 0; j < 3; ++j) {                                           \
            int r0 = (wv * 3 + j) * 16;                                         \
            int rs = r0 + dr4; if (rs > 133) rs = 133;                          \
            gl_lds16(xp + (size_t)(s0 + rs) * DIN_ + (cc) * 32 + sch,           \
                     &As[buf][r0 * 32]);                                        \
        }                                                                       \
    } while (0)

#define STAGE_B(cc, t, buf) do {                                                \
        const unsigned short* wp = w_eff + (size_t)(t) * (DOUT_ * DIN_) +       \
                                   (cc) * 32;                                   \
        _Pragma("unroll")                                                       \
        for (int j = 0; j < 4; ++j) {                                           \
            int r0 = (wv * 4 + j) * 16;                                         \
            gl_lds16(wp + (size_t)(co0 + r0 + dr4) * DIN_ + sch,                \
                     &Bs[buf][r0 * 32]);                                        \
        }                                                                       \
    } while (0)

    f32x4 acc[4][8] = {};

    STAGE_A(0, 0);
    STAGE_B(0, 0, 0);
    int bcur = 0;

    for (int cc = 0; cc < 16; ++cc) {
        const int ca = cc & 1;
        for (int t = 0; t < 7; ++t) {
            int bnext = bcur + 1; if (bnext == 3) bnext = 0;
            if (t < 6) {
                STAGE_B(cc, t + 1, bnext);
                asm volatile("s_waitcnt vmcnt(4)" ::: "memory");
            } else if (cc < 15) {
                STAGE_B(cc + 1, 0, bnext);
                STAGE_A(cc + 1, ca ^ 1);
                asm volatile("s_waitcnt vmcnt(7)" ::: "memory");
            } else {
                asm volatile("s_waitcnt vmcnt(0)" ::: "memory");
            }
            __builtin_amdgcn_s_barrier();

            const unsigned short* Ab = &As[ca][0];
            const unsigned short* Bb = &Bs[bcur][0];
            bf16x8 af[4], bfv[8];
#pragma unroll
            for (int m = 0; m < 4; ++m) {
                int r = wrow + m * 16 + c16 + t;
                af[m] = *reinterpret_cast<const bf16x8*>(
                    &Ab[r * 32 + ((g ^ (r & 3)) << 3)]);
            }
#pragma unroll
            for (int n = 0; n < 8; ++n) {
                int rb = wcol + n * 16 + c16;
                bfv[n] = *reinterpret_cast<const bf16x8*>(
                    &Bb[rb * 32 + ((g ^ (rb & 3)) << 3)]);
            }
            __builtin_amdgcn_s_setprio(1);
#pragma unroll
            for (int m = 0; m < 4; ++m)
#pragma unroll
                for (int n = 0; n < 8; ++n)
                    acc[m][n] = __builtin_amdgcn_mfma_f32_16x16x32_bf16(
                        af[m], bfv[n], acc[m][n], 0, 0, 0);
            __builtin_amdgcn_s_setprio(0);
            bcur = bnext;
        }
    }

    // Q branch: fold 1/sqrt(DH) * log2(e) so attn softmax runs in exp2 domain
    float osc = (tensor == 0) ? 0.125f * 1.44269504f : 1.0f;
#pragma unroll
    for (int m = 0; m < 4; ++m) {
        int rowb = s0 + wrow + m * 16 + 4 * g;
#pragma unroll
        for (int n = 0; n < 8; ++n) {
            int col = co0 + wcol + n * 16 + c16;
            float be = b_eff[col];
#pragma unroll
            for (int ri = 0; ri < 4; ++ri)
                out[(size_t)(rowb + ri) * DOUT_ + col] =
                    f2bf((acc[m][n][ri] + be) * osc);
        }
    }
#undef STAGE_A
#undef STAGE_B
}

// ---------------- kernel 2b: transpose V per (b,h): [S][DH] -> [DH][S] --------
__global__ void transpose_v(const unsigned short* __restrict__ vh,
                            unsigned short* __restrict__ vt) {
    __shared__ alignas(16) unsigned short T[64 * 64];
    int bid = blockIdx.x;
    int stile = bid & 31;
    int bh = bid >> 5;
    int b = bh >> 3;
    int h = bh & 7;
    int s0 = stile * 64;
    const unsigned short* src = vh + ((size_t)b * S_ + s0) * DOUT_ + h * DH_;
    unsigned short* dst = vt + (size_t)bh * DH_ * S_ + s0;
    int tid = threadIdx.x;
#pragma unroll
    for (int it = 0; it < 2; ++it) {
        int idx = tid + it * 256;
        int s = idx >> 3, dhc = idx & 7;
        uint4 val = *reinterpret_cast<const uint4*>(&src[(size_t)s * DOUT_ + dhc * 8]);
        *reinterpret_cast<uint4*>(&T[s * 64 + ((dhc ^ (s & 7) ^ ((s >> 3) & 7)) << 3)]) = val;
    }
    __syncthreads();
#pragma unroll
    for (int it = 0; it < 2; ++it) {
        int idx = tid + it * 256;
        int dh = idx >> 3, sc = idx & 7;
        unsigned short tmp[8];
#pragma unroll
        for (int j = 0; j < 8; ++j) {
            int s = sc * 8 + j;
            tmp[j] = T[s * 64 + (((dh >> 3) ^ (s & 7) ^ ((s >> 3) & 7)) << 3) + (dh & 7)];
        }
        *reinterpret_cast<uint4*>(&dst[(size_t)dh * S_ + sc * 8]) =
            *reinterpret_cast<const uint4*>(tmp);
    }
}

// ---------------- kernel 3: flash attention (identity bid; exp2 softmax) -----
__global__ __launch_bounds__(256, 4) void attn(const unsigned short* __restrict__ qh,
                     const unsigned short* __restrict__ kh,
                     const unsigned short* __restrict__ vt,
                     float* __restrict__ out) {
    __shared__ alignas(16) unsigned short Ks[2][64 * 64];
    __shared__ alignas(16) unsigned short Vs[2][64 * 64];
    __shared__ alignas(16) unsigned short Ps[4][16 * 64];

    const int tid = threadIdx.x;
    const int l = tid & 63;
    const int wv = tid >> 6;
    const int g = l >> 4;
    const int c16 = l & 15;

    const int bid = blockIdx.x;           // identity mapping (R6 swizzle hurt)
    const int qt = bid & 31;
    const int bh = bid >> 5;
    const int b = bh >> 3;
    const int h = bh & 7;
    const int s0 = qt * 64;

    const unsigned short* qp = qh + (size_t)b * S_ * DOUT_ + h * DH_;
    const unsigned short* kp = kh + (size_t)b * S_ * DOUT_ + h * DH_;
    const unsigned short* vp = vt + (size_t)bh * DH_ * S_;

    bf16x8 qf[2];
    {
        int row = s0 + wv * 16 + c16;
        qf[0] = *reinterpret_cast<const bf16x8*>(&qp[(size_t)row * DOUT_ + 8 * g]);
        qf[1] = *reinterpret_cast<const bf16x8*>(&qp[(size_t)row * DOUT_ + 32 + 8 * g]);
    }

    const int l3 = l >> 3;
    const int kchunk8 = ((l & 7) ^ l3) * 8;

#define STAGE(kt, buf) do {                                                          \
        const unsigned short* kgp = kp + (size_t)(kt) * 64 * DOUT_;                  \
        const unsigned short* vgp = vp + (size_t)(kt) * 64;                          \
        _Pragma("unroll")                                                            \
        for (int i = 0; i < 2; ++i) {                                                \
            int K0 = wv * 16 + i * 8;                                                \
            gl_lds16(kgp + (size_t)(K0 + l3) * DOUT_ + kchunk8, &Ks[buf][K0 * 64]);  \
            gl_lds16(vgp + (size_t)(K0 + l3) * S_   + kchunk8, &Vs[buf][K0 * 64]);   \
        }                                                                            \
    } while (0)

    f32x4 oacc[4] = {};
    float mrow[4], lrow[4];
#pragma unroll
    for (int r = 0; r < 4; ++r) { mrow[r] = -1e30f; lrow[r] = 0.f; }

    char* PsB = (char*)&Ps[wv][0];

    STAGE(0, 0);

    const int NT = S_ / 64;
    for (int kt = 0; kt < NT; ++kt) {
        const int cur = kt & 1;
        if (kt + 1 < NT) {
            STAGE(kt + 1, 1 - cur);
            asm volatile("s_waitcnt vmcnt(4)" ::: "memory");
        } else {
            asm volatile("s_waitcnt vmcnt(0)" ::: "memory");
        }
        __builtin_amdgcn_s_barrier();

        // ---- S = Q K^T (scores already in log2 domain) ----
        const char* KsB = (const char*)&Ks[cur][0];
        f32x4 sf[4] = {};
#pragma unroll
        for (int kk = 0; kk < 2; ++kk) {
            bf16x8 kf[4];
#pragma unroll
            for (int n = 0; n < 4; ++n)
                kf[n] = *reinterpret_cast<const bf16x8*>(
                    KsB + (n * 16 + c16) * 128 + (((4 * kk + g) ^ (l & 7)) << 4));
            __builtin_amdgcn_s_setprio(1);
#pragma unroll
            for (int n = 0; n < 4; ++n)
                sf[n] = __builtin_amdgcn_mfma_f32_16x16x32_bf16(qf[kk], kf[n], sf[n], 0, 0, 0);
            __builtin_amdgcn_s_setprio(0);
        }

        // ---- online softmax, exp2 domain, defer-max (THR=8) ----
        float mx[4];
#pragma unroll
        for (int r = 0; r < 4; ++r) {
            float m0 = fmaxf(fmaxf(sf[0][r], sf[1][r]), fmaxf(sf[2][r], sf[3][r]));
            m0 = fmaxf(m0, __shfl_xor(m0, 1, 64));
            m0 = fmaxf(m0, __shfl_xor(m0, 2, 64));
            m0 = fmaxf(m0, __shfl_xor(m0, 4, 64));
            m0 = fmaxf(m0, __shfl_xor(m0, 8, 64));
            mx[r] = m0;
        }
        bool ok = (mx[0] <= mrow[0] + 8.f) && (mx[1] <= mrow[1] + 8.f) &&
                  (mx[2] <= mrow[2] + 8.f) && (mx[3] <= mrow[3] + 8.f);
        if (!__all(ok)) {
#pragma unroll
            for (int r = 0; r < 4; ++r) {
                float mnew = fmaxf(mrow[r], mx[r]);
                float corr = fexp2(mrow[r] - mnew);
                mrow[r] = mnew;
                lrow[r] *= corr;
                oacc[0][r] *= corr;
                oacc[1][r] *= corr;
                oacc[2][r] *= corr;
                oacc[3][r] *= corr;
            }
        }
        float rs[4] = {0.f, 0.f, 0.f, 0.f};
#pragma unroll
        for (int n = 0; n < 4; ++n)
#pragma unroll
            for (int r = 0; r < 4; ++r) {
                float p = fexp2(sf[n][r] - mrow[r]);
                sf[n][r] = p;
                rs[r] += p;
            }
#pragma unroll
        for (int r = 0; r < 4; ++r) {
            rs[r] += __shfl_xor(rs[r], 1, 64);
            rs[r] += __shfl_xor(rs[r], 2, 64);
            rs[r] += __shfl_xor(rs[r], 4, 64);
            rs[r] += __shfl_xor(rs[r], 8, 64);
            lrow[r] += rs[r];
        }

        // ---- P -> LDS (row = 4g+r, col = key = n*16+c16), swizzled ----
#pragma unroll
        for (int n = 0; n < 4; ++n) {
            int cb = 2 * n + (c16 >> 3);
#pragma unroll
            for (int r = 0; r < 4; ++r) {
                int row = 4 * g + r;
                int phys = cb ^ (row & 7) ^ (row >> 3);
                *(unsigned short*)(PsB + row * 128 + (phys << 4) + ((l & 7) << 1)) =
                    f2bf(sf[n][r]);
            }
        }

        // ---- O += P V ----
        const char* VsB = (const char*)&Vs[cur][0];
#pragma unroll
        for (int kk = 0; kk < 2; ++kk) {
            int physr = (4 * kk + g) ^ (c16 & 7) ^ (c16 >> 3);
            bf16x8 pf = *reinterpret_cast<const bf16x8*>(PsB + c16 * 128 + (physr << 4));
            bf16x8 vfr[4];
#pragma unroll
            for (int n = 0; n < 4; ++n)
                vfr[n] = *reinterpret_cast<const bf16x8*>(
                    VsB + (n * 16 + c16) * 128 + (((4 * kk + g) ^ (l & 7)) << 4));
            __builtin_amdgcn_s_setprio(1);
#pragma unroll
            for (int n = 0; n < 4; ++n)
                oacc[n] = __builtin_amdgcn_mfma_f32_16x16x32_bf16(pf, vfr[n], oacc[n], 0, 0, 0);
            __builtin_amdgcn_s_setprio(0);
        }
        __builtin_amdgcn_s_barrier();
    }

    float* op = out + (size_t)b * S_ * DOUT_ + h * DH_;
#pragma unroll
    for (int r = 0; r < 4; ++r) {
        int row = s0 + wv * 16 + 4 * g + r;
        float inv = 1.0f / lrow[r];
#pragma unroll
        for (int n = 0; n < 4; ++n)
            op[(size_t)row * DOUT_ + n * 16 + c16] = oacc[n][r] * inv;
    }
#undef STAGE
}

// ---------------- kernel 4: LayerNorm over 512 features, wave per row --------
__global__ void lnorm(float* __restrict__ out, const float* __restrict__ gamma,
                      const float* __restrict__ beta) {
    int tid = threadIdx.x;
    int lane = tid & 63;
    int wv = tid >> 6;
    int row = blockIdx.x * 4 + wv;
    float* p = out + (size_t)row * DOUT_;
    float4 v0 = *reinterpret_cast<const float4*>(&p[lane * 8]);
    float4 v1 = *reinterpret_cast<const float4*>(&p[lane * 8 + 4]);
    float s = v0.x + v0.y + v0.z + v0.w + v1.x + v1.y + v1.z + v1.w;
    float sq = v0.x * v0.x + v0.y * v0.y + v0.z * v0.z + v0.w * v0.w +
               v1.x * v1.x + v1.y * v1.y + v1.z * v1.z + v1.w * v1.w;
    for (int off = 1; off < 64; off <<= 1) {
        s += __shfl_xor(s, off, 64);
        sq += __shfl_xor(sq, off, 64);
    }
    float mu = s * (1.0f / 512.0f);
    float var = sq * (1.0f / 512.0f) - mu * mu;
    float rstd = rsqrtf(fmaxf(var, 0.f) + EPS_);
    float4 g0 = *reinterpret_cast<const float4*>(&gamma[lane * 8]);
    float4 g1 = *reinterpret_cast<const float4*>(&gamma[lane * 8 + 4]);
    float4 b0 = *reinterpret_cast<const float4*>(&beta[lane * 8]);
    float4 b1 = *reinterpret_cast<const float4*>(&beta[lane * 8 + 4]);
    float4 o0, o1;
    o0.x = (v0.x - mu) * rstd * g0.x + b0.x;
    o0.y = (v0.y - mu) * rstd * g0.y + b0.y;
    o0.z = (v0.z - mu) * rstd * g0.z + b0.z;
    o0.w = (v0.w - mu) * rstd * g0.w + b0.w;
    o1.x = (v1.x - mu) * rstd * g1.x + b1.x;
    o1.y = (v1.y - mu) * rstd * g1.y + b1.y;
    o1.z = (v1.z - mu) * rstd * g1.z + b1.z;
    o1.w = (v1.w - mu) * rstd * g1.w + b1.w;
    *reinterpret_cast<float4*>(&p[lane * 8]) = o0;
    *reinterpret_cast<float4*>(&p[lane * 8 + 4]) = o1;
}

extern "C" void kernel_launch(void* const* d_in, const int* in_sizes, int n_in,
                              void* d_out, int out_size, void* d_ws, size_t ws_size,
                              hipStream_t stream) {
    const float* q        = (const float*)d_in[0];
    const float* k        = (const float*)d_in[1];
    const float* v        = (const float*)d_in[2];
    const float* conv_w   = (const float*)d_in[3];
    const float* conv_b   = (const float*)d_in[4];
    const float* bn_gamma = (const float*)d_in[5];
    const float* bn_beta  = (const float*)d_in[6];
    const float* bn_mean  = (const float*)d_in[7];
    const float* bn_var   = (const float*)d_in[8];
    const float* ln_gamma = (const float*)d_in[9];
    const float* ln_beta  = (const float*)d_in[10];

    unsigned short* qh    = (unsigned short*)d_ws;
    unsigned short* kh    = qh + (size_t)B_ * S_ * DOUT_;
    unsigned short* vh    = kh + (size_t)B_ * S_ * DOUT_;
    unsigned short* w_eff = vh + (size_t)B_ * S_ * DOUT_;
    float* b_eff          = (float*)(w_eff + (size_t)7 * DOUT_ * DIN_);
    unsigned short* xb    = (unsigned short*)(b_eff + DOUT_);
    unsigned short* vt    = xb;   // alias: vt written only after conv consumed xb

    float* out = (float*)d_out;

    cast_x<<<dim3(6162), dim3(256), 0, stream>>>(q, k, v, xb);
    prep_w<<<dim3(7168), dim3(256), 0, stream>>>(conv_w, conv_b, bn_gamma, bn_beta,
                                                 bn_mean, bn_var, w_eff, b_eff);
    conv_bn<<<dim3(384), dim3(256), 0, stream>>>(xb, w_eff, b_eff, qh);
    transpose_v<<<dim3(1024), dim3(256), 0, stream>>>(vh, vt);
    attn<<<dim3(1024), dim3(256), 0, stream>>>(qh, kh, vt, out);
    lnorm<<<dim3(2048), dim3(256), 0, stream>>>(out, ln_gamma, ln_beta);
}

// Round 8
// 188.004 us; speedup vs baseline: 1.1648x; 1.1648x over previous
//
#include <hip/hip_runtime.h>
#include <hip/hip_bf16.h>

// Self_Attention: conv1d(k=7,pad=3)+BN on q/k/v -> MHA (H=8, DH=64) -> LayerNorm
// R8: attn compute core restructured — swapped QK^T (mfma(K,Q)) and swapped
// PV (mfma(V,P)) so each lane owns softmax row q=c16: in-lane reduce + 2
// shuffles (was 32), P stays in registers (cvt_pk + 16 bpermute, no Ps LDS),
// float4 C-write. Staging/pipeline/grid identical to R7. Others frozen.

#define B_ 4
#define S_ 2048
#define DIN_ 512
#define DOUT_ 512
#define H_ 8
#define DH_ 64
#define EPS_ 1e-5f
#define SP_ 2054   // S + 6 halo rows

using bf16x8 = __attribute__((ext_vector_type(8))) short;
using f32x4  = __attribute__((ext_vector_type(4))) float;

__device__ __forceinline__ unsigned short f2bf(float x) {
    union { float f; unsigned u; } v; v.f = x;
    unsigned r = v.u + 0x7FFF + ((v.u >> 16) & 1);
    return (unsigned short)(r >> 16);
}

__device__ __forceinline__ unsigned cvt2(float lo, float hi) {
    unsigned r;
    asm("v_cvt_pk_bf16_f32 %0, %1, %2" : "=v"(r) : "v"(lo), "v"(hi));
    return r;
}

__device__ __forceinline__ float fexp2(float x) {
    float r;
    asm("v_exp_f32 %0, %1" : "=v"(r) : "v"(x));
    return r;
}

typedef __attribute__((address_space(1))) const unsigned int GU32;
typedef __attribute__((address_space(3))) unsigned int LU32;
__device__ __forceinline__ void gl_lds16(const void* g, void* l) {
    __builtin_amdgcn_global_load_lds((GU32*)g, (LU32*)l, 16, 0, 0);
}

// ---------------- kernel 0: cast q/k/v f32 -> bf16 padded [3][4][SP][512] ----
__global__ void cast_x(const float* __restrict__ q, const float* __restrict__ k,
                       const float* __restrict__ v, unsigned short* __restrict__ xb) {
    int i = blockIdx.x * 256 + threadIdx.x;
    int row = i >> 6;
    int cin = (i & 63) * 8;
    int tb = row / SP_;
    int pr = row - tb * SP_;
    int tensor = tb >> 2;
    int b = tb & 3;
    unsigned short* dst = xb + (size_t)row * DIN_ + cin;
    if (pr < 3 || pr >= SP_ - 3) {
        *reinterpret_cast<uint4*>(dst) = make_uint4(0, 0, 0, 0);
    } else {
        const float* src = (tensor == 0 ? q : (tensor == 1 ? k : v)) +
                           ((size_t)b * S_ + (pr - 3)) * DIN_ + cin;
        float4 a0 = *reinterpret_cast<const float4*>(src);
        float4 a1 = *reinterpret_cast<const float4*>(src + 4);
        uint4 o;
        o.x = cvt2(a0.x, a0.y); o.y = cvt2(a0.z, a0.w);
        o.z = cvt2(a1.x, a1.y); o.w = cvt2(a1.z, a1.w);
        *reinterpret_cast<uint4*>(dst) = o;
    }
}

// ---------------- kernel 1: fold BN into weights, cast to bf16 [t][co][ci] ----
__global__ void prep_w(const float* __restrict__ w, const float* __restrict__ cb,
                       const float* __restrict__ gamma, const float* __restrict__ beta,
                       const float* __restrict__ mean, const float* __restrict__ var,
                       unsigned short* __restrict__ w_eff, float* __restrict__ b_eff) {
    int gid = blockIdx.x * blockDim.x + threadIdx.x;
    if (gid < DOUT_) {
        float sc = gamma[gid] * rsqrtf(var[gid] + EPS_);
        b_eff[gid] = (cb[gid] - mean[gid]) * sc + beta[gid];
    }
    int total = 7 * DOUT_ * DIN_;
    for (int i = gid; i < total; i += gridDim.x * blockDim.x) {
        int t = i / (DOUT_ * DIN_);
        int rem = i - t * (DOUT_ * DIN_);
        int co = rem >> 9;
        int ci = rem & 511;
        float sc = gamma[co] * rsqrtf(var[co] + EPS_);
        w_eff[i] = f2bf(w[(co * DIN_ + ci) * 7 + t] * sc);
    }
}

// ---------------- kernel 2: conv+BN implicit GEMM, gl_lds pipelined ----------
__global__ __launch_bounds__(256, 2) void conv_bn(
        const unsigned short* __restrict__ xb,
        const unsigned short* __restrict__ w_eff,
        const float* __restrict__ b_eff,
        unsigned short* __restrict__ out3) {
    __shared__ alignas(16) unsigned short As[2][192 * 32];
    __shared__ alignas(16) unsigned short Bs[3][256 * 32];

    int orig = blockIdx.x;
    int bid = (orig & 7) * 48 + (orig >> 3);   // XCD-chunked, 384 = 8*48
    int tensor = bid >> 7;
    int rem = bid & 127;
    int batch = rem >> 5;
    int stile = (rem >> 1) & 15;
    int cotile = rem & 1;
    int s0 = stile * 128;
    int co0 = cotile * 256;

    const unsigned short* xp = xb + (size_t)(tensor * 4 + batch) * SP_ * DIN_;
    unsigned short* out = out3 + (size_t)tensor * (B_ * S_ * DOUT_) +
                          (size_t)batch * S_ * DOUT_;

    const int tid = threadIdx.x;
    const int l = tid & 63;
    const int wv = tid >> 6;
    const int g = l >> 4;
    const int c16 = l & 15;
    const int wrow = (wv >> 1) * 64;
    const int wcol = (wv & 1) * 128;

    const int dr4 = l >> 2;
    const int sch = ((l & 3) ^ (dr4 & 3)) << 3;

#define STAGE_A(cc, buf) do {                                                   \
        _Pragma("unroll")                                                       \
        for (int j = 0; j < 3; ++j) {                                           \
            int r0 = (wv * 3 + j) * 16;                                         \
            int rs = r0 + dr4; if (rs > 133) rs = 133;                          \
            gl_lds16(xp + (size_t)(s0 + rs) * DIN_ + (cc) * 32 + sch,           \
                     &As[buf][r0 * 32]);                                        \
        }                                                                       \
    } while (0)

#define STAGE_B(cc, t, buf) do {                                                \
        const unsigned short* wp = w_eff + (size_t)(t) * (DOUT_ * DIN_) +       \
                                   (cc) * 32;                                   \
        _Pragma("unroll")                                                       \
        for (int j = 0; j < 4; ++j) {                                           \
            int r0 = (wv * 4 + j) * 16;                                         \
            gl_lds16(wp + (size_t)(co0 + r0 + dr4) * DIN_ + sch,                \
                     &Bs[buf][r0 * 32]);                                        \
        }                                                                       \
    } while (0)

    f32x4 acc[4][8] = {};

    STAGE_A(0, 0);
    STAGE_B(0, 0, 0);
    int bcur = 0;

    for (int cc = 0; cc < 16; ++cc) {
        const int ca = cc & 1;
        for (int t = 0; t < 7; ++t) {
            int bnext = bcur + 1; if (bnext == 3) bnext = 0;
            if (t < 6) {
                STAGE_B(cc, t + 1, bnext);
                asm volatile("s_waitcnt vmcnt(4)" ::: "memory");
            } else if (cc < 15) {
                STAGE_B(cc + 1, 0, bnext);
                STAGE_A(cc + 1, ca ^ 1);
                asm volatile("s_waitcnt vmcnt(7)" ::: "memory");
            } else {
                asm volatile("s_waitcnt vmcnt(0)" ::: "memory");
            }
            __builtin_amdgcn_s_barrier();

            const unsigned short* Ab = &As[ca][0];
            const unsigned short* Bb = &Bs[bcur][0];
            bf16x8 af[4], bfv[8];
#pragma unroll
            for (int m = 0; m < 4; ++m) {
                int r = wrow + m * 16 + c16 + t;
                af[m] = *reinterpret_cast<const bf16x8*>(
                    &Ab[r * 32 + ((g ^ (r & 3)) << 3)]);
            }
#pragma unroll
            for (int n = 0; n < 8; ++n) {
                int rb = wcol + n * 16 + c16;
                bfv[n] = *reinterpret_cast<const bf16x8*>(
                    &Bb[rb * 32 + ((g ^ (rb & 3)) << 3)]);
            }
            __builtin_amdgcn_s_setprio(1);
#pragma unroll
            for (int m = 0; m < 4; ++m)
#pragma unroll
                for (int n = 0; n < 8; ++n)
                    acc[m][n] = __builtin_amdgcn_mfma_f32_16x16x32_bf16(
                        af[m], bfv[n], acc[m][n], 0, 0, 0);
            __builtin_amdgcn_s_setprio(0);
            bcur = bnext;
        }
    }

    // Q branch: fold 1/sqrt(DH) * log2(e) so attn softmax runs in exp2 domain
    float osc = (tensor == 0) ? 0.125f * 1.44269504f : 1.0f;
#pragma unroll
    for (int m = 0; m < 4; ++m) {
        int rowb = s0 + wrow + m * 16 + 4 * g;
#pragma unroll
        for (int n = 0; n < 8; ++n) {
            int col = co0 + wcol + n * 16 + c16;
            float be = b_eff[col];
#pragma unroll
            for (int ri = 0; ri < 4; ++ri)
                out[(size_t)(rowb + ri) * DOUT_ + col] =
                    f2bf((acc[m][n][ri] + be) * osc);
        }
    }
#undef STAGE_A
#undef STAGE_B
}

// ---------------- kernel 2b: transpose V per (b,h): [S][DH] -> [DH][S] --------
__global__ void transpose_v(const unsigned short* __restrict__ vh,
                            unsigned short* __restrict__ vt) {
    __shared__ alignas(16) unsigned short T[64 * 64];
    int bid = blockIdx.x;
    int stile = bid & 31;
    int bh = bid >> 5;
    int b = bh >> 3;
    int h = bh & 7;
    int s0 = stile * 64;
    const unsigned short* src = vh + ((size_t)b * S_ + s0) * DOUT_ + h * DH_;
    unsigned short* dst = vt + (size_t)bh * DH_ * S_ + s0;
    int tid = threadIdx.x;
#pragma unroll
    for (int it = 0; it < 2; ++it) {
        int idx = tid + it * 256;
        int s = idx >> 3, dhc = idx & 7;
        uint4 val = *reinterpret_cast<const uint4*>(&src[(size_t)s * DOUT_ + dhc * 8]);
        *reinterpret_cast<uint4*>(&T[s * 64 + ((dhc ^ (s & 7) ^ ((s >> 3) & 7)) << 3)]) = val;
    }
    __syncthreads();
#pragma unroll
    for (int it = 0; it < 2; ++it) {
        int idx = tid + it * 256;
        int dh = idx >> 3, sc = idx & 7;
        unsigned short tmp[8];
#pragma unroll
        for (int j = 0; j < 8; ++j) {
            int s = sc * 8 + j;
            tmp[j] = T[s * 64 + (((dh >> 3) ^ (s & 7) ^ ((s >> 3) & 7)) << 3) + (dh & 7)];
        }
        *reinterpret_cast<uint4*>(&dst[(size_t)dh * S_ + sc * 8]) =
            *reinterpret_cast<const uint4*>(tmp);
    }
}

// ---------------- kernel 3: flash attention, swapped-MFMA in-register softmax
// K LDS:  [64 keys][128B], phys chunk = logical ^ (key&7)   (gl_lds staged)
// Vt LDS: [64 dh ][128B], phys chunk = logical ^ (dh&7)     (gl_lds staged)
// sf[n][r] = S[q=c16][key=n*16+4g+r]; oacc[n][r] = O[q=c16][dh=n*16+4g+r]
__global__ __launch_bounds__(256, 4) void attn(const unsigned short* __restrict__ qh,
                     const unsigned short* __restrict__ kh,
                     const unsigned short* __restrict__ vt,
                     float* __restrict__ out) {
    __shared__ alignas(16) unsigned short Ks[2][64 * 64];
    __shared__ alignas(16) unsigned short Vs[2][64 * 64];

    const int tid = threadIdx.x;
    const int l = tid & 63;
    const int wv = tid >> 6;
    const int g = l >> 4;
    const int c16 = l & 15;

    const int bid = blockIdx.x;           // identity mapping
    const int qt = bid & 31;
    const int bh = bid >> 5;
    const int b = bh >> 3;
    const int h = bh & 7;
    const int s0 = qt * 64;

    const unsigned short* qp = qh + (size_t)b * S_ * DOUT_ + h * DH_;
    const unsigned short* kp = kh + (size_t)b * S_ * DOUT_ + h * DH_;
    const unsigned short* vp = vt + (size_t)bh * DH_ * S_;

    bf16x8 qf[2];
    {
        int row = s0 + wv * 16 + c16;
        qf[0] = *reinterpret_cast<const bf16x8*>(&qp[(size_t)row * DOUT_ + 8 * g]);
        qf[1] = *reinterpret_cast<const bf16x8*>(&qp[(size_t)row * DOUT_ + 32 + 8 * g]);
    }

    const int l3 = l >> 3;
    const int kchunk8 = ((l & 7) ^ l3) * 8;

#define STAGE(kt, buf) do {                                                          \
        const unsigned short* kgp = kp + (size_t)(kt) * 64 * DOUT_;                  \
        const unsigned short* vgp = vp + (size_t)(kt) * 64;                          \
        _Pragma("unroll")                                                            \
        for (int i = 0; i < 2; ++i) {                                                \
            int K0 = wv * 16 + i * 8;                                                \
            gl_lds16(kgp + (size_t)(K0 + l3) * DOUT_ + kchunk8, &Ks[buf][K0 * 64]);  \
            gl_lds16(vgp + (size_t)(K0 + l3) * S_   + kchunk8, &Vs[buf][K0 * 64]);   \
        }                                                                            \
    } while (0)

    f32x4 oacc[4] = {};
    float mrow = -1e30f, lrow = 0.f;

    // P-redistribution lane constants: sources in own c16 column
    const int sA = ((l & 16) << 1) | c16;   // lane (2*(g&1), c16)
    const int sB = sA + 16;                  // lane (2*(g&1)+1, c16)
    const bool hi = (l & 32) != 0;           // g>=2 -> n0 = 2kk+1

    STAGE(0, 0);

    const int NT = S_ / 64;
    for (int kt = 0; kt < NT; ++kt) {
        const int cur = kt & 1;
        if (kt + 1 < NT) {
            STAGE(kt + 1, 1 - cur);
            asm volatile("s_waitcnt vmcnt(4)" ::: "memory");
        } else {
            asm volatile("s_waitcnt vmcnt(0)" ::: "memory");
        }
        __builtin_amdgcn_s_barrier();

        // ---- S^T tile: sf[n] = mfma(K, Q): lane holds S[q=c16][key=n*16+4g+r]
        const char* KsB = (const char*)&Ks[cur][0];
        f32x4 sf[4] = {};
#pragma unroll
        for (int kk = 0; kk < 2; ++kk) {
            bf16x8 kf[4];
#pragma unroll
            for (int n = 0; n < 4; ++n)
                kf[n] = *reinterpret_cast<const bf16x8*>(
                    KsB + (n * 16 + c16) * 128 + (((4 * kk + g) ^ (l & 7)) << 4));
            __builtin_amdgcn_s_setprio(1);
#pragma unroll
            for (int n = 0; n < 4; ++n)
                sf[n] = __builtin_amdgcn_mfma_f32_16x16x32_bf16(kf[n], qf[kk], sf[n], 0, 0, 0);
            __builtin_amdgcn_s_setprio(0);
        }

        // ---- in-register softmax (exp2 domain), row q=c16 per lane ----
        float t0 = fmaxf(fmaxf(sf[0][0], sf[0][1]), fmaxf(sf[0][2], sf[0][3]));
        float t1 = fmaxf(fmaxf(sf[1][0], sf[1][1]), fmaxf(sf[1][2], sf[1][3]));
        float t2 = fmaxf(fmaxf(sf[2][0], sf[2][1]), fmaxf(sf[2][2], sf[2][3]));
        float t3 = fmaxf(fmaxf(sf[3][0], sf[3][1]), fmaxf(sf[3][2], sf[3][3]));
        float m0 = fmaxf(fmaxf(t0, t1), fmaxf(t2, t3));
        m0 = fmaxf(m0, __shfl_xor(m0, 16, 64));
        m0 = fmaxf(m0, __shfl_xor(m0, 32, 64));
        if (!__all(m0 <= mrow + 8.f)) {
            float mnew = fmaxf(mrow, m0);
            float corr = fexp2(mrow - mnew);
            mrow = mnew;
            lrow *= corr;
#pragma unroll
            for (int n = 0; n < 4; ++n) {
                oacc[n][0] *= corr; oacc[n][1] *= corr;
                oacc[n][2] *= corr; oacc[n][3] *= corr;
            }
        }
        unsigned pk[4][2];
        float rsn[4];
#pragma unroll
        for (int n = 0; n < 4; ++n) {
            float p0 = fexp2(sf[n][0] - mrow);
            float p1 = fexp2(sf[n][1] - mrow);
            float p2 = fexp2(sf[n][2] - mrow);
            float p3 = fexp2(sf[n][3] - mrow);
            rsn[n] = (p0 + p1) + (p2 + p3);
            pk[n][0] = cvt2(p0, p1);
            pk[n][1] = cvt2(p2, p3);
        }
        float rs = (rsn[0] + rsn[1]) + (rsn[2] + rsn[3]);
        rs += __shfl_xor(rs, 16, 64);
        rs += __shfl_xor(rs, 32, 64);
        lrow += rs;

        // ---- O^T += mfma(V, P): lane accumulates O[q=c16][dh=n*16+4g+r] ----
        const char* VsB = (const char*)&Vs[cur][0];
#pragma unroll
        for (int kk = 0; kk < 2; ++kk) {
            // build pf = P[q=c16][keys 32kk+8g .. +7] from pk via bpermute
            unsigned a0 = __shfl((int)pk[2 * kk][0], sA, 64);
            unsigned a1 = __shfl((int)pk[2 * kk][1], sA, 64);
            unsigned a2 = __shfl((int)pk[2 * kk][0], sB, 64);
            unsigned a3 = __shfl((int)pk[2 * kk][1], sB, 64);
            unsigned b0 = __shfl((int)pk[2 * kk + 1][0], sA, 64);
            unsigned b1 = __shfl((int)pk[2 * kk + 1][1], sA, 64);
            unsigned b2 = __shfl((int)pk[2 * kk + 1][0], sB, 64);
            unsigned b3 = __shfl((int)pk[2 * kk + 1][1], sB, 64);
            union { unsigned w[4]; bf16x8 v; } pu;
            pu.w[0] = hi ? b0 : a0;
            pu.w[1] = hi ? b1 : a1;
            pu.w[2] = hi ? b2 : a2;
            pu.w[3] = hi ? b3 : a3;
            bf16x8 vfr[4];
#pragma unroll
            for (int n = 0; n < 4; ++n)
                vfr[n] = *reinterpret_cast<const bf16x8*>(
                    VsB + (n * 16 + c16) * 128 + (((4 * kk + g) ^ (l & 7)) << 4));
            __builtin_amdgcn_s_setprio(1);
#pragma unroll
            for (int n = 0; n < 4; ++n)
                oacc[n] = __builtin_amdgcn_mfma_f32_16x16x32_bf16(vfr[n], pu.v, oacc[n], 0, 0, 0);
            __builtin_amdgcn_s_setprio(0);
        }
        __builtin_amdgcn_s_barrier();
    }

    // epilogue: O[q=c16][dh=n*16+4g+r] -> float4 stores, own-lane lrow
    {
        int row = s0 + wv * 16 + c16;
        float inv = 1.0f / lrow;
        float* op = out + (size_t)b * S_ * DOUT_ + h * DH_ + (size_t)row * DOUT_;
#pragma unroll
        for (int n = 0; n < 4; ++n) {
            f32x4 o = oacc[n];
            o[0] *= inv; o[1] *= inv; o[2] *= inv; o[3] *= inv;
            *reinterpret_cast<f32x4*>(&op[n * 16 + 4 * g]) = o;
        }
    }
#undef STAGE
}

// ---------------- kernel 4: LayerNorm over 512 features, wave per row --------
__global__ void lnorm(float* __restrict__ out, const float* __restrict__ gamma,
                      const float* __restrict__ beta) {
    int tid = threadIdx.x;
    int lane = tid & 63;
    int wv = tid >> 6;
    int row = blockIdx.x * 4 + wv;
    float* p = out + (size_t)row * DOUT_;
    float4 v0 = *reinterpret_cast<const float4*>(&p[lane * 8]);
    float4 v1 = *reinterpret_cast<const float4*>(&p[lane * 8 + 4]);
    float s = v0.x + v0.y + v0.z + v0.w + v1.x + v1.y + v1.z + v1.w;
    float sq = v0.x * v0.x + v0.y * v0.y + v0.z * v0.z + v0.w * v0.w +
               v1.x * v1.x + v1.y * v1.y + v1.z * v1.z + v1.w * v1.w;
    for (int off = 1; off < 64; off <<= 1) {
        s += __shfl_xor(s, off, 64);
        sq += __shfl_xor(sq, off, 64);
    }
    float mu = s * (1.0f / 512.0f);
    float var = sq * (1.0f / 512.0f) - mu * mu;
    float rstd = rsqrtf(fmaxf(var, 0.f) + EPS_);
    float4 g0 = *reinterpret_cast<const float4*>(&gamma[lane * 8]);
    float4 g1 = *reinterpret_cast<const float4*>(&gamma[lane * 8 + 4]);
    float4 b0 = *reinterpret_cast<const float4*>(&beta[lane * 8]);
    float4 b1 = *reinterpret_cast<const float4*>(&beta[lane * 8 + 4]);
    float4 o0, o1;
    o0.x = (v0.x - mu) * rstd * g0.x + b0.x;
    o0.y = (v0.y - mu) * rstd * g0.y + b0.y;
    o0.z = (v0.z - mu) * rstd * g0.z + b0.z;
    o0.w = (v0.w - mu) * rstd * g0.w + b0.w;
    o1.x = (v1.x - mu) * rstd * g1.x + b1.x;
    o1.y = (v1.y - mu) * rstd * g1.y + b1.y;
    o1.z = (v1.z - mu) * rstd * g1.z + b1.z;
    o1.w = (v1.w - mu) * rstd * g1.w + b1.w;
    *reinterpret_cast<float4*>(&p[lane * 8]) = o0;
    *reinterpret_cast<float4*>(&p[lane * 8 + 4]) = o1;
}

extern "C" void kernel_launch(void* const* d_in, const int* in_sizes, int n_in,
                              void* d_out, int out_size, void* d_ws, size_t ws_size,
                              hipStream_t stream) {
    const float* q        = (const float*)d_in[0];
    const float* k        = (const float*)d_in[1];
    const float* v        = (const float*)d_in[2];
    const float* conv_w   = (const float*)d_in[3];
    const float* conv_b   = (const float*)d_in[4];
    const float* bn_gamma = (const float*)d_in[5];
    const float* bn_beta  = (const float*)d_in[6];
    const float* bn_mean  = (const float*)d_in[7];
    const float* bn_var   = (const float*)d_in[8];
    const float* ln_gamma = (const float*)d_in[9];
    const float* ln_beta  = (const float*)d_in[10];

    unsigned short* qh    = (unsigned short*)d_ws;
    unsigned short* kh    = qh + (size_t)B_ * S_ * DOUT_;
    unsigned short* vh    = kh + (size_t)B_ * S_ * DOUT_;
    unsigned short* w_eff = vh + (size_t)B_ * S_ * DOUT_;
    float* b_eff          = (float*)(w_eff + (size_t)7 * DOUT_ * DIN_);
    unsigned short* xb    = (unsigned short*)(b_eff + DOUT_);
    unsigned short* vt    = xb;   // alias: vt written only after conv consumed xb

    float* out = (float*)d_out;

    cast_x<<<dim3(6162), dim3(256), 0, stream>>>(q, k, v, xb);
    prep_w<<<dim3(7168), dim3(256), 0, stream>>>(conv_w, conv_b, bn_gamma, bn_beta,
                                                 bn_mean, bn_var, w_eff, b_eff);
    conv_bn<<<dim3(384), dim3(256), 0, stream>>>(xb, w_eff, b_eff, qh);
    transpose_v<<<dim3(1024), dim3(256), 0, stream>>>(vh, vt);
    attn<<<dim3(1024), dim3(256), 0, stream>>>(qh, kh, vt, out);
    lnorm<<<dim3(2048), dim3(256), 0, stream>>>(out, ln_gamma, ln_beta);
}